// Round 1
// baseline (443.960 us; speedup 1.0000x reference)
//
#include <hip/hip_runtime.h>
#include <stdint.h>

typedef unsigned short u16;

#define S_ 4096
#define B_ 8
#define H_ 1024
#define F_ 1024
#define M_ (S_ * B_)   // 32768
#define N_ F_          // 1024
#define K_ H_          // 1024

#define BM 128
#define BN 128
#define BK 64

typedef short short8 __attribute__((ext_vector_type(8)));
typedef float floatx4 __attribute__((ext_vector_type(4)));

// RNE float -> bf16 bits (values are well-behaved: no NaN/Inf in this problem)
__device__ __forceinline__ u16 f2bf(float f) {
    union { float f; uint32_t u; } c;
    c.f = f;
    uint32_t u = c.u;
    uint32_t r = (u + 0x7fffu + ((u >> 16) & 1u)) >> 16;
    return (u16)r;
}

// async 16B/lane global -> LDS (dest = wave-uniform base + lane*16)
__device__ __forceinline__ void async_load16(const void* gptr, void* lptr) {
    __builtin_amdgcn_global_load_lds(
        (const __attribute__((address_space(1))) uint32_t*)gptr,
        (__attribute__((address_space(3))) uint32_t*)lptr,
        16 /*size*/, 0 /*offset*/, 0 /*aux*/);
}

// ---------------------------------------------------------------------------
// Kernel 1: transpose + cast W (K_ x N_ fp32, row-major) -> Bt (N_ x K_ bf16)
// ---------------------------------------------------------------------------
__global__ __launch_bounds__(256) void transpose_cast_kernel(
    const float* __restrict__ w, u16* __restrict__ bt)
{
    __shared__ float tile[32][33];
    const int tx = threadIdx.x;  // 0..31
    const int ty = threadIdx.y;  // 0..7
    const int n0 = blockIdx.x * 32;
    const int k0 = blockIdx.y * 32;
#pragma unroll
    for (int j = 0; j < 4; ++j)
        tile[ty + j * 8][tx] = w[(size_t)(k0 + ty + j * 8) * N_ + n0 + tx];
    __syncthreads();
#pragma unroll
    for (int j = 0; j < 4; ++j)
        bt[(size_t)(n0 + ty + j * 8) * K_ + k0 + tx] =
            f2bf(tile[tx][ty + j * 8]);
}

// ---------------------------------------------------------------------------
// Kernel 2: LayerNorm, one block (256 threads) per row of H_=1024.
// Writes fp32 ln_out (output 1) and bf16 copy for the GEMM A operand.
// ---------------------------------------------------------------------------
__global__ __launch_bounds__(256) void ln_kernel(
    const float* __restrict__ x, const float* __restrict__ scale,
    const float* __restrict__ bias, float* __restrict__ ln_out,
    u16* __restrict__ ln_bf16)
{
    const int row = blockIdx.x;
    const int tid = threadIdx.x;
    const float4 v = reinterpret_cast<const float4*>(x + (size_t)row * H_)[tid];

    float s  = v.x + v.y + v.z + v.w;
    float sq = v.x * v.x + v.y * v.y + v.z * v.z + v.w * v.w;
#pragma unroll
    for (int off = 32; off >= 1; off >>= 1) {
        s  += __shfl_down(s, off, 64);
        sq += __shfl_down(sq, off, 64);
    }
    __shared__ float red[8];
    const int wave = tid >> 6, lane = tid & 63;
    if (lane == 0) { red[wave] = s; red[4 + wave] = sq; }
    __syncthreads();
    const float Ssum = red[0] + red[1] + red[2] + red[3];
    const float Qsum = red[4] + red[5] + red[6] + red[7];
    const float mu   = Ssum * (1.0f / H_);
    const float var  = Qsum * (1.0f / H_) - mu * mu;
    const float rstd = rsqrtf(var + 1e-6f);

    const float4 sc = reinterpret_cast<const float4*>(scale)[tid];
    const float4 bi = reinterpret_cast<const float4*>(bias)[tid];
    float4 y;
    y.x = (v.x - mu) * rstd * sc.x + bi.x;
    y.y = (v.y - mu) * rstd * sc.y + bi.y;
    y.z = (v.z - mu) * rstd * sc.z + bi.z;
    y.w = (v.w - mu) * rstd * sc.w + bi.w;

    reinterpret_cast<float4*>(ln_out + (size_t)row * H_)[tid] = y;

    ushort4 h;
    h.x = f2bf(y.x); h.y = f2bf(y.y); h.z = f2bf(y.z); h.w = f2bf(y.w);
    reinterpret_cast<ushort4*>(ln_bf16 + (size_t)row * H_)[tid] = h;
}

// ---------------------------------------------------------------------------
// Kernel 3: GEMM C = A * Bt^T.  A: M_ x K_ bf16 row-major (ln_out bf16),
// Bt: N_ x K_ bf16 row-major (W transposed), C: M_ x N_ fp32 row-major.
// 128x128 block tile, BK=64, 4 waves in 2x2, each wave 64x64 via 4x4
// mfma_f32_16x16x32_bf16, global_load_lds 16B staging, 2-barrier K-loop.
// ---------------------------------------------------------------------------
__global__ __launch_bounds__(256, 2) void gemm_bt_kernel(
    const u16* __restrict__ A, const u16* __restrict__ Bt,
    float* __restrict__ C)
{
    __shared__ __align__(16) u16 As[BM * BK];
    __shared__ __align__(16) u16 Bs[BN * BK];

    const int tid  = threadIdx.x;
    const int wave = tid >> 6;
    const int lane = tid & 63;
    const int wm   = wave >> 1;  // 0..1
    const int wn   = wave & 1;   // 0..1
    const int row0 = blockIdx.y * BM;
    const int col0 = blockIdx.x * BN;

    floatx4 acc[4][4];
#pragma unroll
    for (int i = 0; i < 4; ++i)
#pragma unroll
        for (int j = 0; j < 4; ++j) acc[i][j] = (floatx4)0.0f;

    // staging: per call each wave fills 8 rows (64 lanes * 16B = 8 rows * 128B)
    const int srow = wave * 8 + (lane >> 3);   // row within 32-row group
    const int scol = (lane & 7) * 8;           // bf16 element col within BK
    const u16* Ag = A + (size_t)(row0 + srow) * K_ + scol;
    const u16* Bg = Bt + (size_t)(col0 + srow) * K_ + scol;
    char* AsBase = (char*)As + (size_t)(wave * 8) * (BK * 2);
    char* BsBase = (char*)Bs + (size_t)(wave * 8) * (BK * 2);

    for (int kt = 0; kt < K_ / BK; ++kt) {
        const int k0 = kt * BK;
#pragma unroll
        for (int i = 0; i < 4; ++i) {
            async_load16(Ag + (size_t)(i * 32) * K_ + k0,
                         AsBase + (size_t)(i * 32) * (BK * 2));
            async_load16(Bg + (size_t)(i * 32) * K_ + k0,
                         BsBase + (size_t)(i * 32) * (BK * 2));
        }
        __syncthreads();  // drains vmcnt -> LDS tiles complete

#pragma unroll
        for (int ks = 0; ks < 2; ++ks) {
            const int kb = ks * 32 + (lane >> 4) * 8;
            short8 af[4], bf[4];
#pragma unroll
            for (int mt = 0; mt < 4; ++mt)
                af[mt] = *reinterpret_cast<const short8*>(
                    &As[(wm * 64 + mt * 16 + (lane & 15)) * BK + kb]);
#pragma unroll
            for (int nt = 0; nt < 4; ++nt)
                bf[nt] = *reinterpret_cast<const short8*>(
                    &Bs[(wn * 64 + nt * 16 + (lane & 15)) * BK + kb]);
#pragma unroll
            for (int mt = 0; mt < 4; ++mt)
#pragma unroll
                for (int nt = 0; nt < 4; ++nt)
                    acc[mt][nt] = __builtin_amdgcn_mfma_f32_16x16x32_bf16(
                        af[mt], bf[nt], acc[mt][nt], 0, 0, 0);
        }
        __syncthreads();  // protect LDS from next iteration's staging
    }

    // epilogue: C/D layout col = lane&15, row = (lane>>4)*4 + reg
#pragma unroll
    for (int mt = 0; mt < 4; ++mt) {
#pragma unroll
        for (int nt = 0; nt < 4; ++nt) {
            const int r0 = row0 + wm * 64 + mt * 16 + (lane >> 4) * 4;
            const int c  = col0 + wn * 64 + nt * 16 + (lane & 15);
#pragma unroll
            for (int r = 0; r < 4; ++r)
                C[(size_t)(r0 + r) * N_ + c] = acc[mt][nt][r];
        }
    }
}

// ---------------------------------------------------------------------------
extern "C" void kernel_launch(void* const* d_in, const int* in_sizes, int n_in,
                              void* d_out, int out_size, void* d_ws, size_t ws_size,
                              hipStream_t stream) {
    const float* x      = (const float*)d_in[0];   // (S,B,H)
    const float* scale  = (const float*)d_in[1];   // (H,)
    const float* lnbias = (const float*)d_in[2];   // (H,)
    const float* weight = (const float*)d_in[3];   // (H,F)

    float* out    = (float*)d_out;                     // (S,B,F)
    float* ln_out = (float*)d_out + (size_t)M_ * N_;   // (S,B,H)

    // workspace layout: [A bf16: M_*K_ u16 = 64 MiB][Bt bf16: N_*K_ u16 = 2 MiB]
    u16* ln_bf16 = (u16*)d_ws;
    u16* bt      = (u16*)d_ws + (size_t)M_ * K_;

    transpose_cast_kernel<<<dim3(N_ / 32, K_ / 32), dim3(32, 8), 0, stream>>>(
        weight, bt);
    ln_kernel<<<M_, 256, 0, stream>>>(x, scale, lnbias, ln_out, ln_bf16);
    gemm_bt_kernel<<<dim3(N_ / BN, M_ / BM), 256, 0, stream>>>(ln_bf16, bt, out);
}

// Round 2
// 430.490 us; speedup vs baseline: 1.0313x; 1.0313x over previous
//
#include <hip/hip_runtime.h>
#include <stdint.h>

typedef unsigned short u16;

#define S_ 4096
#define B_ 8
#define H_ 1024
#define F_ 1024
#define M_ (S_ * B_)   // 32768
#define N_ F_          // 1024
#define K_ H_          // 1024

#define BM 128
#define BN 128
#define BK 64

typedef short short8 __attribute__((ext_vector_type(8)));
typedef float floatx4 __attribute__((ext_vector_type(4)));

// RNE float -> bf16 bits (values are well-behaved: no NaN/Inf in this problem)
__device__ __forceinline__ u16 f2bf(float f) {
    union { float f; uint32_t u; } c;
    c.f = f;
    uint32_t u = c.u;
    uint32_t r = (u + 0x7fffu + ((u >> 16) & 1u)) >> 16;
    return (u16)r;
}

// async 16B/lane global -> LDS (dest = wave-uniform base + lane*16)
__device__ __forceinline__ void async_load16(const void* gptr, void* lptr) {
    __builtin_amdgcn_global_load_lds(
        (const __attribute__((address_space(1))) uint32_t*)gptr,
        (__attribute__((address_space(3))) uint32_t*)lptr,
        16 /*size*/, 0 /*offset*/, 0 /*aux*/);
}

// ---------------------------------------------------------------------------
// Kernel 1: transpose + cast W (K_ x N_ fp32, row-major) -> Bt (N_ x K_ bf16)
// ---------------------------------------------------------------------------
__global__ __launch_bounds__(256) void transpose_cast_kernel(
    const float* __restrict__ w, u16* __restrict__ bt)
{
    __shared__ float tile[32][33];
    const int tx = threadIdx.x;  // 0..31
    const int ty = threadIdx.y;  // 0..7
    const int n0 = blockIdx.x * 32;
    const int k0 = blockIdx.y * 32;
#pragma unroll
    for (int j = 0; j < 4; ++j)
        tile[ty + j * 8][tx] = w[(size_t)(k0 + ty + j * 8) * N_ + n0 + tx];
    __syncthreads();
#pragma unroll
    for (int j = 0; j < 4; ++j)
        bt[(size_t)(n0 + ty + j * 8) * K_ + k0 + tx] =
            f2bf(tile[tx][ty + j * 8]);
}

// ---------------------------------------------------------------------------
// Kernel 2: LayerNorm, one block (256 threads) per row of H_=1024.
// Writes fp32 ln_out (output 1) and bf16 copy for the GEMM A operand.
// ---------------------------------------------------------------------------
__global__ __launch_bounds__(256) void ln_kernel(
    const float* __restrict__ x, const float* __restrict__ scale,
    const float* __restrict__ bias, float* __restrict__ ln_out,
    u16* __restrict__ ln_bf16)
{
    const int row = blockIdx.x;
    const int tid = threadIdx.x;
    const float4 v = reinterpret_cast<const float4*>(x + (size_t)row * H_)[tid];

    float s  = v.x + v.y + v.z + v.w;
    float sq = v.x * v.x + v.y * v.y + v.z * v.z + v.w * v.w;
#pragma unroll
    for (int off = 32; off >= 1; off >>= 1) {
        s  += __shfl_down(s, off, 64);
        sq += __shfl_down(sq, off, 64);
    }
    __shared__ float red[8];
    const int wave = tid >> 6, lane = tid & 63;
    if (lane == 0) { red[wave] = s; red[4 + wave] = sq; }
    __syncthreads();
    const float Ssum = red[0] + red[1] + red[2] + red[3];
    const float Qsum = red[4] + red[5] + red[6] + red[7];
    const float mu   = Ssum * (1.0f / H_);
    const float var  = Qsum * (1.0f / H_) - mu * mu;
    const float rstd = rsqrtf(var + 1e-6f);

    const float4 sc = reinterpret_cast<const float4*>(scale)[tid];
    const float4 bi = reinterpret_cast<const float4*>(bias)[tid];
    float4 y;
    y.x = (v.x - mu) * rstd * sc.x + bi.x;
    y.y = (v.y - mu) * rstd * sc.y + bi.y;
    y.z = (v.z - mu) * rstd * sc.z + bi.z;
    y.w = (v.w - mu) * rstd * sc.w + bi.w;

    reinterpret_cast<float4*>(ln_out + (size_t)row * H_)[tid] = y;

    ushort4 h;
    h.x = f2bf(y.x); h.y = f2bf(y.y); h.z = f2bf(y.z); h.w = f2bf(y.w);
    reinterpret_cast<ushort4*>(ln_bf16 + (size_t)row * H_)[tid] = h;
}

// ---------------------------------------------------------------------------
// Kernel 3: GEMM C = A * Bt^T.  A: M_ x K_ bf16 row-major (ln_out bf16),
// Bt: N_ x K_ bf16 row-major (W transposed), C: M_ x N_ fp32 row-major.
// 128x128 block tile, BK=64, 4 waves in 2x2, each wave 64x64 via 4x4
// mfma_f32_16x16x32_bf16, global_load_lds 16B staging.
//
// LDS layout uses an XOR chunk swizzle: LDS slot (row, c) holds global
// 16B-chunk (c ^ (row & 7)) of that row. Implemented on the staging side by
// permuting each lane's *global* fetch address (the global_load_lds LDS dst
// is fixed at base + lane*16 and cannot be padded). This makes every
// ds_read_b128 fragment fetch bank-uniform (8 words/bank) instead of the
// 16-rows-same-chunk pattern (16 words/bank = 2x LDS serialization).
//
// Grid is 1-D with an XCD swizzle: all 8 N-tiles of an M-tile share
// bid % 8 so they land on the same XCD (round-robin heuristic) and share
// the A-tile in that XCD's L2 (8 x 256KB A + 2MB Bt = 4MB = L2 size).
// ---------------------------------------------------------------------------
__global__ __launch_bounds__(256) void gemm_bt_kernel(
    const u16* __restrict__ A, const u16* __restrict__ Bt,
    float* __restrict__ C)
{
    __shared__ __align__(16) u16 As[BM * BK];
    __shared__ __align__(16) u16 Bs[BN * BK];

    const int tid  = threadIdx.x;
    const int wave = tid >> 6;
    const int lane = tid & 63;
    const int wm   = wave >> 1;  // 0..1
    const int wn   = wave & 1;   // 0..1

    // XCD swizzle: by = (bid>>6)*8 + (bid&7), bx = (bid>>3)&7
    const int bid  = blockIdx.x;
    const int bx   = (bid >> 3) & 7;
    const int by   = ((bid >> 6) << 3) | (bid & 7);
    const int row0 = by * BM;
    const int col0 = bx * BN;

    floatx4 acc[4][4];
#pragma unroll
    for (int i = 0; i < 4; ++i)
#pragma unroll
        for (int j = 0; j < 4; ++j) acc[i][j] = (floatx4)0.0f;

    // staging: per call each wave fills 8 rows (64 lanes * 16B = 8 rows * 128B)
    // lane (r=lane>>3, c=lane&7) fetches global chunk (c ^ r) of row r
    const int srow = wave * 8 + (lane >> 3);             // row within 32-row group
    const int scol = (((lane & 7) ^ (lane >> 3)) * 8);   // swizzled bf16 col
    const u16* Ag = A + (size_t)(row0 + srow) * K_ + scol;
    const u16* Bg = Bt + (size_t)(col0 + srow) * K_ + scol;
    char* AsBase = (char*)As + (size_t)(wave * 8) * (BK * 2);
    char* BsBase = (char*)Bs + (size_t)(wave * 8) * (BK * 2);

    for (int kt = 0; kt < K_ / BK; ++kt) {
        const int k0 = kt * BK;
#pragma unroll
        for (int i = 0; i < 4; ++i) {
            async_load16(Ag + (size_t)(i * 32) * K_ + k0,
                         AsBase + (size_t)(i * 32) * (BK * 2));
            async_load16(Bg + (size_t)(i * 32) * K_ + k0,
                         BsBase + (size_t)(i * 32) * (BK * 2));
        }
        __syncthreads();  // drains vmcnt -> LDS tiles complete

#pragma unroll
        for (int ks = 0; ks < 2; ++ks) {
            short8 af[4], bf[4];
#pragma unroll
            for (int mt = 0; mt < 4; ++mt) {
                const int r = wm * 64 + mt * 16 + (lane & 15);
                const int q = ks * 4 + (lane >> 4);       // 16B chunk index
                const int c = q ^ (r & 7);                // XOR de-swizzle
                af[mt] = *reinterpret_cast<const short8*>(
                    (const char*)As + (size_t)r * (BK * 2) + c * 16);
            }
#pragma unroll
            for (int nt = 0; nt < 4; ++nt) {
                const int r = wn * 64 + nt * 16 + (lane & 15);
                const int q = ks * 4 + (lane >> 4);
                const int c = q ^ (r & 7);
                bf[nt] = *reinterpret_cast<const short8*>(
                    (const char*)Bs + (size_t)r * (BK * 2) + c * 16);
            }
#pragma unroll
            for (int mt = 0; mt < 4; ++mt)
#pragma unroll
                for (int nt = 0; nt < 4; ++nt)
                    acc[mt][nt] = __builtin_amdgcn_mfma_f32_16x16x32_bf16(
                        af[mt], bf[nt], acc[mt][nt], 0, 0, 0);
        }
        __syncthreads();  // protect LDS from next iteration's staging
    }

    // epilogue: C/D layout col = lane&15, row = (lane>>4)*4 + reg
#pragma unroll
    for (int mt = 0; mt < 4; ++mt) {
#pragma unroll
        for (int nt = 0; nt < 4; ++nt) {
            const int r0 = row0 + wm * 64 + mt * 16 + (lane >> 4) * 4;
            const int c  = col0 + wn * 64 + nt * 16 + (lane & 15);
#pragma unroll
            for (int r = 0; r < 4; ++r)
                C[(size_t)(r0 + r) * N_ + c] = acc[mt][nt][r];
        }
    }
}

// ---------------------------------------------------------------------------
extern "C" void kernel_launch(void* const* d_in, const int* in_sizes, int n_in,
                              void* d_out, int out_size, void* d_ws, size_t ws_size,
                              hipStream_t stream) {
    const float* x      = (const float*)d_in[0];   // (S,B,H)
    const float* scale  = (const float*)d_in[1];   // (H,)
    const float* lnbias = (const float*)d_in[2];   // (H,)
    const float* weight = (const float*)d_in[3];   // (H,F)

    float* out    = (float*)d_out;                     // (S,B,F)
    float* ln_out = (float*)d_out + (size_t)M_ * N_;   // (S,B,H)

    // workspace layout: [A bf16: M_*K_ u16 = 64 MiB][Bt bf16: N_*K_ u16 = 2 MiB]
    u16* ln_bf16 = (u16*)d_ws;
    u16* bt      = (u16*)d_ws + (size_t)M_ * K_;

    transpose_cast_kernel<<<dim3(N_ / 32, K_ / 32), dim3(32, 8), 0, stream>>>(
        weight, bt);
    ln_kernel<<<M_, 256, 0, stream>>>(x, scale, lnbias, ln_out, ln_bf16);
    gemm_bt_kernel<<<(M_ / BM) * (N_ / BN), 256, 0, stream>>>(ln_bf16, bt, out);
}